// Round 1
// baseline (1664.881 us; speedup 1.0000x reference)
//
#include <hip/hip_runtime.h>

// Round 0: correct baseline.
//   x,W -> fp16; QKV + out-proj via mfma_f32_16x16x32_f16 (128x128 tile, fp32 accum);
//   attention = per-thread-row flash, fp32 math, K/V staged fp32 in LDS (broadcast reads).
// ws layout (fp16 elems): xh[8.4M] | Wcat[3.1M] | Woh[1.0M] | qh[8.4M] | kh[8.4M] | vh[8.4M]
//   y reuses xh. Total ~75.5 MB.

typedef _Float16 fp16x8 __attribute__((ext_vector_type(8)));
typedef float f32x4 __attribute__((ext_vector_type(4)));

#define LOG2E 1.44269504088896f

// ---------------- fp32 -> fp16 cast ----------------
__global__ __launch_bounds__(256) void cast_f32_f16(const float* __restrict__ s,
                                                    _Float16* __restrict__ d, int n) {
  int i = (blockIdx.x * 256 + threadIdx.x) * 8;
  if (i + 8 > n) return;
  float4 a = *(const float4*)(s + i);
  float4 b = *(const float4*)(s + i + 4);
  fp16x8 h;
  h[0] = (_Float16)a.x; h[1] = (_Float16)a.y; h[2] = (_Float16)a.z; h[3] = (_Float16)a.w;
  h[4] = (_Float16)b.x; h[5] = (_Float16)b.y; h[6] = (_Float16)b.z; h[7] = (_Float16)b.w;
  *(fp16x8*)(d + i) = h;
}

// ---------------- QKV projection GEMM ----------------
// A = xh [8192 x 1024] row-major. B = Wcat [3072 x 1024] (i.e. W in [n][k] = B^T form).
// out[m][n] = sum_k A[m][k]*W[n][k] + bias[n], written to q/k/v in [B,H,T,DH] fp16.
// Block tile 128x128, K-step 32. 4 waves; wave w owns rows (w&1)*64, cols (w>>1)*64.
__global__ __launch_bounds__(256) void gemm_qkv(
    const _Float16* __restrict__ A, const _Float16* __restrict__ W,
    const float* __restrict__ bq, const float* __restrict__ bk, const float* __restrict__ bv,
    _Float16* __restrict__ qo, _Float16* __restrict__ ko, _Float16* __restrict__ vo) {
  __shared__ __align__(16) _Float16 As[128 * 40];  // pad 32->40 (2-way max, free)
  __shared__ __align__(16) _Float16 Bs[128 * 40];
  const int tid = threadIdx.x;
  const int m0 = blockIdx.x * 128;
  const int n0 = blockIdx.y * 128;
  const int w = tid >> 6, lane = tid & 63;
  const int lr = lane & 15, quad = lane >> 4;
  const int wm = (w & 1) * 64, wn = (w >> 1) * 64;

  f32x4 acc[4][4];
#pragma unroll
  for (int i = 0; i < 4; ++i)
#pragma unroll
    for (int j = 0; j < 4; ++j) acc[i][j] = (f32x4){0.f, 0.f, 0.f, 0.f};

  const int sr1 = tid >> 2, sc = (tid & 3) * 8, sr2 = sr1 + 64;
  const _Float16* Ag1 = A + (size_t)(m0 + sr1) * 1024 + sc;
  const _Float16* Ag2 = A + (size_t)(m0 + sr2) * 1024 + sc;
  const _Float16* Bg1 = W + (size_t)(n0 + sr1) * 1024 + sc;
  const _Float16* Bg2 = W + (size_t)(n0 + sr2) * 1024 + sc;

  for (int kt = 0; kt < 32; ++kt) {
    const int kk = kt * 32;
    uint4 a1 = *(const uint4*)(Ag1 + kk);
    uint4 a2 = *(const uint4*)(Ag2 + kk);
    uint4 b1 = *(const uint4*)(Bg1 + kk);
    uint4 b2 = *(const uint4*)(Bg2 + kk);
    __syncthreads();
    *(uint4*)&As[sr1 * 40 + sc] = a1;
    *(uint4*)&As[sr2 * 40 + sc] = a2;
    *(uint4*)&Bs[sr1 * 40 + sc] = b1;
    *(uint4*)&Bs[sr2 * 40 + sc] = b2;
    __syncthreads();
    fp16x8 af[4], bf[4];
#pragma unroll
    for (int i = 0; i < 4; ++i) {
      af[i] = *(const fp16x8*)&As[(wm + i * 16 + lr) * 40 + quad * 8];
      bf[i] = *(const fp16x8*)&Bs[(wn + i * 16 + lr) * 40 + quad * 8];
    }
#pragma unroll
    for (int i = 0; i < 4; ++i)
#pragma unroll
      for (int j = 0; j < 4; ++j)
        acc[i][j] = __builtin_amdgcn_mfma_f32_16x16x32_f16(af[i], bf[j], acc[i][j], 0, 0, 0);
  }

  // epilogue: n0 block is fully inside one of Wq/Wk/Wv (1024 % 128 == 0)
  const int wsel = n0 >> 10;
  const float* bias = (wsel == 0) ? bq : (wsel == 1) ? bk : bv;
  _Float16* dst = (wsel == 0) ? qo : (wsel == 1) ? ko : vo;
#pragma unroll
  for (int j = 0; j < 4; ++j) {
    const int n = n0 + wn + j * 16 + lr;
    const int nm = n & 1023;
    const float bval = bias[nm];
    const int h = nm >> 6, dd = nm & 63;
#pragma unroll
    for (int i = 0; i < 4; ++i) {
      const int mbase = m0 + wm + i * 16 + quad * 4;
#pragma unroll
      for (int r = 0; r < 4; ++r) {
        const int m = mbase + r;
        const int b = m >> 11, t = m & 2047;
        dst[((size_t)(b * 16 + h) * 2048 + t) * 64 + dd] = (_Float16)(acc[i][j][r] + bval);
      }
    }
  }
}

// ---------------- out projection GEMM ----------------
__global__ __launch_bounds__(256) void gemm_out(
    const _Float16* __restrict__ A, const _Float16* __restrict__ W,
    const float* __restrict__ bo, float* __restrict__ out) {
  __shared__ __align__(16) _Float16 As[128 * 40];
  __shared__ __align__(16) _Float16 Bs[128 * 40];
  const int tid = threadIdx.x;
  const int m0 = blockIdx.x * 128;
  const int n0 = blockIdx.y * 128;
  const int w = tid >> 6, lane = tid & 63;
  const int lr = lane & 15, quad = lane >> 4;
  const int wm = (w & 1) * 64, wn = (w >> 1) * 64;

  f32x4 acc[4][4];
#pragma unroll
  for (int i = 0; i < 4; ++i)
#pragma unroll
    for (int j = 0; j < 4; ++j) acc[i][j] = (f32x4){0.f, 0.f, 0.f, 0.f};

  const int sr1 = tid >> 2, sc = (tid & 3) * 8, sr2 = sr1 + 64;
  const _Float16* Ag1 = A + (size_t)(m0 + sr1) * 1024 + sc;
  const _Float16* Ag2 = A + (size_t)(m0 + sr2) * 1024 + sc;
  const _Float16* Bg1 = W + (size_t)(n0 + sr1) * 1024 + sc;
  const _Float16* Bg2 = W + (size_t)(n0 + sr2) * 1024 + sc;

  for (int kt = 0; kt < 32; ++kt) {
    const int kk = kt * 32;
    uint4 a1 = *(const uint4*)(Ag1 + kk);
    uint4 a2 = *(const uint4*)(Ag2 + kk);
    uint4 b1 = *(const uint4*)(Bg1 + kk);
    uint4 b2 = *(const uint4*)(Bg2 + kk);
    __syncthreads();
    *(uint4*)&As[sr1 * 40 + sc] = a1;
    *(uint4*)&As[sr2 * 40 + sc] = a2;
    *(uint4*)&Bs[sr1 * 40 + sc] = b1;
    *(uint4*)&Bs[sr2 * 40 + sc] = b2;
    __syncthreads();
    fp16x8 af[4], bf[4];
#pragma unroll
    for (int i = 0; i < 4; ++i) {
      af[i] = *(const fp16x8*)&As[(wm + i * 16 + lr) * 40 + quad * 8];
      bf[i] = *(const fp16x8*)&Bs[(wn + i * 16 + lr) * 40 + quad * 8];
    }
#pragma unroll
    for (int i = 0; i < 4; ++i)
#pragma unroll
      for (int j = 0; j < 4; ++j)
        acc[i][j] = __builtin_amdgcn_mfma_f32_16x16x32_f16(af[i], bf[j], acc[i][j], 0, 0, 0);
  }

#pragma unroll
  for (int j = 0; j < 4; ++j) {
    const int n = n0 + wn + j * 16 + lr;
    const float bval = bo[n];
#pragma unroll
    for (int i = 0; i < 4; ++i) {
      const int mbase = m0 + wm + i * 16 + quad * 4;
#pragma unroll
      for (int r = 0; r < 4; ++r) {
        out[(size_t)(mbase + r) * 1024 + n] = acc[i][j][r] + bval;
      }
    }
  }
}

// ---------------- causal flash attention ----------------
// q,k,v: [B*H, T, 64] fp16. One thread per query row (rows interleaved across the
// block's 4 waves so every wave touches every K-tile). K/V tiles (64x64) staged to
// LDS as fp32; inner reads are wave-broadcast (conflict-free). Online softmax with
// ballot-gated max-rescale. y: [B*T, C] fp16 (token-major for the out-proj GEMM).
__global__ __launch_bounds__(256) void attn(
    const _Float16* __restrict__ q, const _Float16* __restrict__ k,
    const _Float16* __restrict__ v, _Float16* __restrict__ y) {
  __shared__ __align__(16) float Ks[64 * 68];  // pad 64->68: write-phase 2-way max
  __shared__ __align__(16) float Vs[64 * 68];
  const int tid = threadIdx.x;
  const int bh = blockIdx.y;
  const int b = bh >> 4, h = bh & 15;
  const int tq = blockIdx.x * 256 + (tid & 63) * 4 + (tid >> 6);

  const _Float16* qp = q + ((size_t)bh * 2048 + tq) * 64;
  float qr[64];
#pragma unroll
  for (int d8 = 0; d8 < 8; ++d8) {
    fp16x8 hv = *(const fp16x8*)(qp + d8 * 8);
#pragma unroll
    for (int i = 0; i < 8; ++i) qr[d8 * 8 + i] = (float)hv[i] * 0.125f;  // 1/sqrt(64)
  }
  float o[64];
#pragma unroll
  for (int d = 0; d < 64; ++d) o[d] = 0.f;
  float m_i = -3e38f, l_i = 0.f;

  const int ntiles = blockIdx.x * 4 + 4;
  const int srow = tid >> 2, scol = (tid & 3) * 16;

  for (int kt = 0; kt < ntiles; ++kt) {
    const _Float16* kg = k + ((size_t)bh * 2048 + kt * 64 + srow) * 64 + scol;
    const _Float16* vg = v + ((size_t)bh * 2048 + kt * 64 + srow) * 64 + scol;
    fp16x8 k1 = *(const fp16x8*)kg, k2 = *(const fp16x8*)(kg + 8);
    fp16x8 v1 = *(const fp16x8*)vg, v2 = *(const fp16x8*)(vg + 8);
    __syncthreads();
#pragma unroll
    for (int i = 0; i < 8; ++i) {
      Ks[srow * 68 + scol + i] = (float)k1[i];
      Ks[srow * 68 + scol + 8 + i] = (float)k2[i];
      Vs[srow * 68 + scol + i] = (float)v1[i];
      Vs[srow * 68 + scol + 8 + i] = (float)v2[i];
    }
    __syncthreads();
    const int kbase = kt * 64;
    for (int kk = 0; kk < 64; ++kk) {
      const float* kr = &Ks[kk * 68];
      float s = 0.f;
#pragma unroll
      for (int d4 = 0; d4 < 16; ++d4) {
        float4 kv = *(const float4*)(kr + d4 * 4);
        s += qr[d4 * 4 + 0] * kv.x + qr[d4 * 4 + 1] * kv.y +
             qr[d4 * 4 + 2] * kv.z + qr[d4 * 4 + 3] * kv.w;
      }
      const bool valid = (kbase + kk) <= tq;
      const float sv = valid ? s : -3e38f;
      if (__ballot(sv > m_i)) {  // rare after warmup; corr==1 for non-updating lanes
        const float mn = fmaxf(m_i, sv);
        const float corr = __builtin_amdgcn_exp2f((m_i - mn) * LOG2E);
        l_i *= corr;
#pragma unroll
        for (int d = 0; d < 64; ++d) o[d] *= corr;
        m_i = mn;
      }
      const float p = valid ? __builtin_amdgcn_exp2f((s - m_i) * LOG2E) : 0.f;
      l_i += p;
      const float* vr = &Vs[kk * 68];
#pragma unroll
      for (int d4 = 0; d4 < 16; ++d4) {
        float4 vv = *(const float4*)(vr + d4 * 4);
        o[d4 * 4 + 0] += p * vv.x;
        o[d4 * 4 + 1] += p * vv.y;
        o[d4 * 4 + 2] += p * vv.z;
        o[d4 * 4 + 3] += p * vv.w;
      }
    }
  }

  const float inv = 1.f / l_i;
  _Float16* yp = y + ((size_t)(b * 2048 + tq)) * 1024 + h * 64;
#pragma unroll
  for (int d8 = 0; d8 < 8; ++d8) {
    fp16x8 hv;
#pragma unroll
    for (int i = 0; i < 8; ++i) hv[i] = (_Float16)(o[d8 * 8 + i] * inv);
    *(fp16x8*)(yp + d8 * 8) = hv;
  }
}

extern "C" void kernel_launch(void* const* d_in, const int* in_sizes, int n_in,
                              void* d_out, int out_size, void* d_ws, size_t ws_size,
                              hipStream_t stream) {
  const float* x  = (const float*)d_in[0];
  const float* Wq = (const float*)d_in[1];
  const float* bq = (const float*)d_in[2];
  const float* Wk = (const float*)d_in[3];
  const float* bk = (const float*)d_in[4];
  const float* Wv = (const float*)d_in[5];
  const float* bv = (const float*)d_in[6];
  const float* Wo = (const float*)d_in[7];
  const float* bo = (const float*)d_in[8];

  _Float16* ws   = (_Float16*)d_ws;
  _Float16* xh   = ws;                    // 8388608 (also reused for y)
  _Float16* Wcat = xh + 8388608;          // 3145728 (Wq|Wk|Wv as [3072][1024])
  _Float16* Woh  = Wcat + 3145728;        // 1048576
  _Float16* qh   = Woh + 1048576;         // 8388608  [B*H, T, 64]
  _Float16* kh   = qh + 8388608;
  _Float16* vh   = kh + 8388608;
  _Float16* yh   = xh;                    // alias: x is dead after gemm_qkv

  cast_f32_f16<<<4096, 256, 0, stream>>>(x, xh, 8388608);
  cast_f32_f16<<<512, 256, 0, stream>>>(Wq, Wcat, 1048576);
  cast_f32_f16<<<512, 256, 0, stream>>>(Wk, Wcat + 1048576, 1048576);
  cast_f32_f16<<<512, 256, 0, stream>>>(Wv, Wcat + 2097152, 1048576);
  cast_f32_f16<<<512, 256, 0, stream>>>(Wo, Woh, 1048576);

  gemm_qkv<<<dim3(64, 24), 256, 0, stream>>>(xh, Wcat, bq, bk, bv, qh, kh, vh);
  attn<<<dim3(8, 64), 256, 0, stream>>>(qh, kh, vh, yh);
  gemm_out<<<dim3(64, 8), 256, 0, stream>>>(yh, Woh, bo, (float*)d_out);
}

// Round 2
// 445.951 us; speedup vs baseline: 3.7333x; 3.7333x over previous
//
#include <hip/hip_runtime.h>

// Round 1: MFMA flash attention.
//   attn rewritten: QK^T and PV on mfma_f32_16x16x32_f16, online softmax in C-layout
//   regs (shfl_xor row reductions), P transposed C->A layout via per-wave private LDS.
//   K staged row-major, V staged transposed (Vt[d][kc]). 128 q-rows/block, 64 keys/iter.
// GEMMs unchanged from round 0 (correctness-proven fragment addressing reused here).

typedef _Float16 fp16x8 __attribute__((ext_vector_type(8)));
typedef float f32x4 __attribute__((ext_vector_type(4)));

#define LOG2E 1.44269504088896f

// ---------------- fp32 -> fp16 cast ----------------
__global__ __launch_bounds__(256) void cast_f32_f16(const float* __restrict__ s,
                                                    _Float16* __restrict__ d, int n) {
  int i = (blockIdx.x * 256 + threadIdx.x) * 8;
  if (i + 8 > n) return;
  float4 a = *(const float4*)(s + i);
  float4 b = *(const float4*)(s + i + 4);
  fp16x8 h;
  h[0] = (_Float16)a.x; h[1] = (_Float16)a.y; h[2] = (_Float16)a.z; h[3] = (_Float16)a.w;
  h[4] = (_Float16)b.x; h[5] = (_Float16)b.y; h[6] = (_Float16)b.z; h[7] = (_Float16)b.w;
  *(fp16x8*)(d + i) = h;
}

// ---------------- QKV projection GEMM ----------------
__global__ __launch_bounds__(256) void gemm_qkv(
    const _Float16* __restrict__ A, const _Float16* __restrict__ W,
    const float* __restrict__ bq, const float* __restrict__ bk, const float* __restrict__ bv,
    _Float16* __restrict__ qo, _Float16* __restrict__ ko, _Float16* __restrict__ vo) {
  __shared__ __align__(16) _Float16 As[128 * 40];
  __shared__ __align__(16) _Float16 Bs[128 * 40];
  const int tid = threadIdx.x;
  const int m0 = blockIdx.x * 128;
  const int n0 = blockIdx.y * 128;
  const int w = tid >> 6, lane = tid & 63;
  const int lr = lane & 15, quad = lane >> 4;
  const int wm = (w & 1) * 64, wn = (w >> 1) * 64;

  f32x4 acc[4][4];
#pragma unroll
  for (int i = 0; i < 4; ++i)
#pragma unroll
    for (int j = 0; j < 4; ++j) acc[i][j] = (f32x4){0.f, 0.f, 0.f, 0.f};

  const int sr1 = tid >> 2, sc = (tid & 3) * 8, sr2 = sr1 + 64;
  const _Float16* Ag1 = A + (size_t)(m0 + sr1) * 1024 + sc;
  const _Float16* Ag2 = A + (size_t)(m0 + sr2) * 1024 + sc;
  const _Float16* Bg1 = W + (size_t)(n0 + sr1) * 1024 + sc;
  const _Float16* Bg2 = W + (size_t)(n0 + sr2) * 1024 + sc;

  for (int kt = 0; kt < 32; ++kt) {
    const int kk = kt * 32;
    uint4 a1 = *(const uint4*)(Ag1 + kk);
    uint4 a2 = *(const uint4*)(Ag2 + kk);
    uint4 b1 = *(const uint4*)(Bg1 + kk);
    uint4 b2 = *(const uint4*)(Bg2 + kk);
    __syncthreads();
    *(uint4*)&As[sr1 * 40 + sc] = a1;
    *(uint4*)&As[sr2 * 40 + sc] = a2;
    *(uint4*)&Bs[sr1 * 40 + sc] = b1;
    *(uint4*)&Bs[sr2 * 40 + sc] = b2;
    __syncthreads();
    fp16x8 af[4], bf[4];
#pragma unroll
    for (int i = 0; i < 4; ++i) {
      af[i] = *(const fp16x8*)&As[(wm + i * 16 + lr) * 40 + quad * 8];
      bf[i] = *(const fp16x8*)&Bs[(wn + i * 16 + lr) * 40 + quad * 8];
    }
#pragma unroll
    for (int i = 0; i < 4; ++i)
#pragma unroll
      for (int j = 0; j < 4; ++j)
        acc[i][j] = __builtin_amdgcn_mfma_f32_16x16x32_f16(af[i], bf[j], acc[i][j], 0, 0, 0);
  }

  const int wsel = n0 >> 10;
  const float* bias = (wsel == 0) ? bq : (wsel == 1) ? bk : bv;
  _Float16* dst = (wsel == 0) ? qo : (wsel == 1) ? ko : vo;
#pragma unroll
  for (int j = 0; j < 4; ++j) {
    const int n = n0 + wn + j * 16 + lr;
    const int nm = n & 1023;
    const float bval = bias[nm];
    const int h = nm >> 6, dd = nm & 63;
#pragma unroll
    for (int i = 0; i < 4; ++i) {
      const int mbase = m0 + wm + i * 16 + quad * 4;
#pragma unroll
      for (int r = 0; r < 4; ++r) {
        const int m = mbase + r;
        const int b = m >> 11, t = m & 2047;
        dst[((size_t)(b * 16 + h) * 2048 + t) * 64 + dd] = (_Float16)(acc[i][j][r] + bval);
      }
    }
  }
}

// ---------------- out projection GEMM ----------------
__global__ __launch_bounds__(256) void gemm_out(
    const _Float16* __restrict__ A, const _Float16* __restrict__ W,
    const float* __restrict__ bo, float* __restrict__ out) {
  __shared__ __align__(16) _Float16 As[128 * 40];
  __shared__ __align__(16) _Float16 Bs[128 * 40];
  const int tid = threadIdx.x;
  const int m0 = blockIdx.x * 128;
  const int n0 = blockIdx.y * 128;
  const int w = tid >> 6, lane = tid & 63;
  const int lr = lane & 15, quad = lane >> 4;
  const int wm = (w & 1) * 64, wn = (w >> 1) * 64;

  f32x4 acc[4][4];
#pragma unroll
  for (int i = 0; i < 4; ++i)
#pragma unroll
    for (int j = 0; j < 4; ++j) acc[i][j] = (f32x4){0.f, 0.f, 0.f, 0.f};

  const int sr1 = tid >> 2, sc = (tid & 3) * 8, sr2 = sr1 + 64;
  const _Float16* Ag1 = A + (size_t)(m0 + sr1) * 1024 + sc;
  const _Float16* Ag2 = A + (size_t)(m0 + sr2) * 1024 + sc;
  const _Float16* Bg1 = W + (size_t)(n0 + sr1) * 1024 + sc;
  const _Float16* Bg2 = W + (size_t)(n0 + sr2) * 1024 + sc;

  for (int kt = 0; kt < 32; ++kt) {
    const int kk = kt * 32;
    uint4 a1 = *(const uint4*)(Ag1 + kk);
    uint4 a2 = *(const uint4*)(Ag2 + kk);
    uint4 b1 = *(const uint4*)(Bg1 + kk);
    uint4 b2 = *(const uint4*)(Bg2 + kk);
    __syncthreads();
    *(uint4*)&As[sr1 * 40 + sc] = a1;
    *(uint4*)&As[sr2 * 40 + sc] = a2;
    *(uint4*)&Bs[sr1 * 40 + sc] = b1;
    *(uint4*)&Bs[sr2 * 40 + sc] = b2;
    __syncthreads();
    fp16x8 af[4], bf[4];
#pragma unroll
    for (int i = 0; i < 4; ++i) {
      af[i] = *(const fp16x8*)&As[(wm + i * 16 + lr) * 40 + quad * 8];
      bf[i] = *(const fp16x8*)&Bs[(wn + i * 16 + lr) * 40 + quad * 8];
    }
#pragma unroll
    for (int i = 0; i < 4; ++i)
#pragma unroll
      for (int j = 0; j < 4; ++j)
        acc[i][j] = __builtin_amdgcn_mfma_f32_16x16x32_f16(af[i], bf[j], acc[i][j], 0, 0, 0);
  }

#pragma unroll
  for (int j = 0; j < 4; ++j) {
    const int n = n0 + wn + j * 16 + lr;
    const float bval = bo[n];
#pragma unroll
    for (int i = 0; i < 4; ++i) {
      const int mbase = m0 + wm + i * 16 + quad * 4;
#pragma unroll
      for (int r = 0; r < 4; ++r) {
        out[(size_t)(mbase + r) * 1024 + n] = acc[i][j][r] + bval;
      }
    }
  }
}

// ---------------- MFMA causal flash attention ----------------
// q,k,v: [B*H, T, 64] fp16. Block = 128 q-rows of one (b,h); 4 waves x 32 q-rows.
// Per 64-key tile: K row-major in LDS, V transposed (Vt[d][kc]).
// QK^T and PV via mfma_f32_16x16x32_f16. P transits C->A layout through a
// per-wave-private LDS region (no barrier needed: same-wave LDS ordering).
// Online softmax state per lane: rows quad*4+r of each 16-row m-tile.
__global__ __launch_bounds__(256) void attn(
    const _Float16* __restrict__ q, const _Float16* __restrict__ k,
    const _Float16* __restrict__ v, _Float16* __restrict__ y) {
  __shared__ __align__(16) _Float16 Ks[64 * 72];       // K[kc][d], pad 64->72
  __shared__ __align__(16) _Float16 Vt[64 * 72];       // V^T[d][kc]
  __shared__ __align__(16) _Float16 Ps[4 * 32 * 72];   // per-wave P[32][64], pad 72
  const int tid = threadIdx.x;
  const int w = tid >> 6, lane = tid & 63;
  const int lr = lane & 15, quad = lane >> 4;
  const int bh = blockIdx.y;
  const int bx = (int)gridDim.x - 1 - (int)blockIdx.x;  // longest blocks first
  const int m0w = bx * 128 + w * 32;                    // wave's first q row
  const size_t base = (size_t)bh * 2048 * 64;
  _Float16* Pw = &Ps[w * 32 * 72];

  // Q fragments, scale 1/8 * log2(e) folded in
  const _Float16 qs = (_Float16)(0.125f * LOG2E);
  fp16x8 qf[2][2];
#pragma unroll
  for (int mi = 0; mi < 2; ++mi)
#pragma unroll
    for (int c = 0; c < 2; ++c) {
      fp16x8 t = *(const fp16x8*)(q + base + (size_t)(m0w + mi * 16 + lr) * 64 + c * 32 + quad * 8);
#pragma unroll
      for (int i = 0; i < 8; ++i) t[i] = t[i] * qs;
      qf[mi][c] = t;
    }

  f32x4 oacc[2][4];  // [m-tile][d-tile]
#pragma unroll
  for (int mi = 0; mi < 2; ++mi)
#pragma unroll
    for (int dt = 0; dt < 4; ++dt) oacc[mi][dt] = (f32x4){0.f, 0.f, 0.f, 0.f};
  float m_i[2][4], l_i[2][4];
#pragma unroll
  for (int mi = 0; mi < 2; ++mi)
#pragma unroll
    for (int r = 0; r < 4; ++r) { m_i[mi][r] = -3e38f; l_i[mi][r] = 0.f; }

  // staging indices
  const int kr = tid >> 2, kcb = (tid & 3) * 16;   // K: row, col-block
  const int vr = tid & 63, vdb = (tid >> 6) * 16;  // V: row (kc), d-block

  const int ntiles = 2 * bx + 2;
  for (int kt = 0; kt < ntiles; ++kt) {
    const _Float16* kg = k + base + (size_t)(kt * 64 + kr) * 64 + kcb;
    const _Float16* vg = v + base + (size_t)(kt * 64 + vr) * 64 + vdb;
    fp16x8 ka = *(const fp16x8*)kg, kb = *(const fp16x8*)(kg + 8);
    fp16x8 va = *(const fp16x8*)vg, vb = *(const fp16x8*)(vg + 8);
    __syncthreads();
    *(fp16x8*)&Ks[kr * 72 + kcb] = ka;
    *(fp16x8*)&Ks[kr * 72 + kcb + 8] = kb;
#pragma unroll
    for (int i = 0; i < 8; ++i) {
      Vt[(vdb + i) * 72 + vr] = va[i];
      Vt[(vdb + 8 + i) * 72 + vr] = vb[i];
    }
    __syncthreads();

    if (m0w + 31 >= kt * 64) {  // wave participates in this tile
      const bool needmask = (kt * 64 + 63) > m0w;
#pragma unroll
      for (int mi = 0; mi < 2; ++mi) {
        // ---- S = Q K^T (16 x 64) ----
        f32x4 sacc[4];
#pragma unroll
        for (int kct = 0; kct < 4; ++kct) sacc[kct] = (f32x4){0.f, 0.f, 0.f, 0.f};
#pragma unroll
        for (int kct = 0; kct < 4; ++kct) {
          fp16x8 kf0 = *(const fp16x8*)&Ks[(kct * 16 + lr) * 72 + quad * 8];
          fp16x8 kf1 = *(const fp16x8*)&Ks[(kct * 16 + lr) * 72 + 32 + quad * 8];
          sacc[kct] = __builtin_amdgcn_mfma_f32_16x16x32_f16(qf[mi][0], kf0, sacc[kct], 0, 0, 0);
          sacc[kct] = __builtin_amdgcn_mfma_f32_16x16x32_f16(qf[mi][1], kf1, sacc[kct], 0, 0, 0);
        }
        // ---- mask + row max ----
        const int qrow0 = m0w + mi * 16 + quad * 4;
        float rmax[4];
#pragma unroll
        for (int r = 0; r < 4; ++r) {
          if (needmask) {
#pragma unroll
            for (int kct = 0; kct < 4; ++kct) {
              const bool valid = (kt * 64 + kct * 16 + lr) <= (qrow0 + r);
              sacc[kct][r] = valid ? sacc[kct][r] : -3e38f;
            }
          }
          rmax[r] = fmaxf(fmaxf(sacc[0][r], sacc[1][r]), fmaxf(sacc[2][r], sacc[3][r]));
        }
#pragma unroll
        for (int off = 1; off < 16; off <<= 1)
#pragma unroll
          for (int r = 0; r < 4; ++r) rmax[r] = fmaxf(rmax[r], __shfl_xor(rmax[r], off));
        // ---- online update ----
        float corr[4], rsum[4];
#pragma unroll
        for (int r = 0; r < 4; ++r) {
          const float mn = fmaxf(m_i[mi][r], rmax[r]);
          corr[r] = __builtin_amdgcn_exp2f(m_i[mi][r] - mn);
          m_i[mi][r] = mn;
          rsum[r] = 0.f;
        }
        // ---- P = exp2(S - m), write to per-wave LDS (C-layout -> row-major) ----
#pragma unroll
        for (int kct = 0; kct < 4; ++kct)
#pragma unroll
          for (int r = 0; r < 4; ++r) {
            const float p = __builtin_amdgcn_exp2f(sacc[kct][r] - m_i[mi][r]);
            rsum[r] += p;
            Pw[(mi * 16 + quad * 4 + r) * 72 + kct * 16 + lr] = (_Float16)p;
          }
#pragma unroll
        for (int off = 1; off < 16; off <<= 1)
#pragma unroll
          for (int r = 0; r < 4; ++r) rsum[r] += __shfl_xor(rsum[r], off);
#pragma unroll
        for (int r = 0; r < 4; ++r) l_i[mi][r] = l_i[mi][r] * corr[r] + rsum[r];
        // ---- rescale O ----
#pragma unroll
        for (int dt = 0; dt < 4; ++dt)
#pragma unroll
          for (int r = 0; r < 4; ++r) oacc[mi][dt][r] *= corr[r];
      }
      // ---- O += P V ---- (P read back in A-operand layout; same-wave LDS ordering)
#pragma unroll
      for (int c = 0; c < 2; ++c) {
        fp16x8 pf[2];
#pragma unroll
        for (int mi = 0; mi < 2; ++mi)
          pf[mi] = *(const fp16x8*)&Pw[(mi * 16 + lr) * 72 + c * 32 + quad * 8];
#pragma unroll
        for (int dt = 0; dt < 4; ++dt) {
          fp16x8 vf = *(const fp16x8*)&Vt[(dt * 16 + lr) * 72 + c * 32 + quad * 8];
#pragma unroll
          for (int mi = 0; mi < 2; ++mi)
            oacc[mi][dt] = __builtin_amdgcn_mfma_f32_16x16x32_f16(pf[mi], vf, oacc[mi][dt], 0, 0, 0);
        }
      }
    }
  }

  // ---- epilogue: y[b*2048 + tq][h*64 + d] ----
  const int b = bh >> 4, h = bh & 15;
#pragma unroll
  for (int mi = 0; mi < 2; ++mi)
#pragma unroll
    for (int r = 0; r < 4; ++r) {
      const float inv = 1.f / l_i[mi][r];
      const int tq = m0w + mi * 16 + quad * 4 + r;
      _Float16* yp = y + ((size_t)(b * 2048 + tq)) * 1024 + h * 64;
#pragma unroll
      for (int dt = 0; dt < 4; ++dt)
        yp[dt * 16 + lr] = (_Float16)(oacc[mi][dt][r] * inv);
    }
}

extern "C" void kernel_launch(void* const* d_in, const int* in_sizes, int n_in,
                              void* d_out, int out_size, void* d_ws, size_t ws_size,
                              hipStream_t stream) {
  const float* x  = (const float*)d_in[0];
  const float* Wq = (const float*)d_in[1];
  const float* bq = (const float*)d_in[2];
  const float* Wk = (const float*)d_in[3];
  const float* bk = (const float*)d_in[4];
  const float* Wv = (const float*)d_in[5];
  const float* bv = (const float*)d_in[6];
  const float* Wo = (const float*)d_in[7];
  const float* bo = (const float*)d_in[8];

  _Float16* ws   = (_Float16*)d_ws;
  _Float16* xh   = ws;                    // 8388608 (also reused for y)
  _Float16* Wcat = xh + 8388608;          // 3145728
  _Float16* Woh  = Wcat + 3145728;        // 1048576
  _Float16* qh   = Woh + 1048576;         // 8388608  [B*H, T, 64]
  _Float16* kh   = qh + 8388608;
  _Float16* vh   = kh + 8388608;
  _Float16* yh   = xh;                    // alias: x is dead after gemm_qkv

  cast_f32_f16<<<4096, 256, 0, stream>>>(x, xh, 8388608);
  cast_f32_f16<<<512, 256, 0, stream>>>(Wq, Wcat, 1048576);
  cast_f32_f16<<<512, 256, 0, stream>>>(Wk, Wcat + 1048576, 1048576);
  cast_f32_f16<<<512, 256, 0, stream>>>(Wv, Wcat + 2097152, 1048576);
  cast_f32_f16<<<512, 256, 0, stream>>>(Wo, Woh, 1048576);

  gemm_qkv<<<dim3(64, 24), 256, 0, stream>>>(xh, Wcat, bq, bk, bv, qh, kh, vh);
  attn<<<dim3(16, 64), 256, 0, stream>>>(qh, kh, vh, yh);
  gemm_out<<<dim3(64, 8), 256, 0, stream>>>(yh, Woh, bo, (float*)d_out);
}

// Round 3
// 347.700 us; speedup vs baseline: 4.7883x; 1.2826x over previous
//
#include <hip/hip_runtime.h>

// Round 3:
//  attn: uniform-work pairing — block = (b,h) x q-tile pair (i, 31-i), 64 q-rows
//        per q-tile, 4 waves x 16 rows; every block does exactly 33 k-tiles.
//  gemms: m97 structure — global_load_lds width=16 into unpadded LDS[128x32],
//        two-barrier K-loop (documented 1.69x over reg-staged m93 structure).

typedef _Float16 fp16x8 __attribute__((ext_vector_type(8)));
typedef float f32x4 __attribute__((ext_vector_type(4)));

#define LOG2E 1.44269504088896f

__device__ __forceinline__ void async_ld16(const _Float16* g, _Float16* l) {
  __builtin_amdgcn_global_load_lds(
      (const __attribute__((address_space(1))) void*)g,
      (__attribute__((address_space(3))) void*)l, 16, 0, 0);
}

// ---------------- fp32 -> fp16 cast ----------------
__global__ __launch_bounds__(256) void cast_f32_f16(const float* __restrict__ s,
                                                    _Float16* __restrict__ d, int n) {
  int i = (blockIdx.x * 256 + threadIdx.x) * 8;
  if (i + 8 > n) return;
  float4 a = *(const float4*)(s + i);
  float4 b = *(const float4*)(s + i + 4);
  fp16x8 h;
  h[0] = (_Float16)a.x; h[1] = (_Float16)a.y; h[2] = (_Float16)a.z; h[3] = (_Float16)a.w;
  h[4] = (_Float16)b.x; h[5] = (_Float16)b.y; h[6] = (_Float16)b.z; h[7] = (_Float16)b.w;
  *(fp16x8*)(d + i) = h;
}

// ---------------- QKV projection GEMM (m97 structure) ----------------
__global__ __launch_bounds__(256) void gemm_qkv(
    const _Float16* __restrict__ A, const _Float16* __restrict__ W,
    const float* __restrict__ bq, const float* __restrict__ bk, const float* __restrict__ bv,
    _Float16* __restrict__ qo, _Float16* __restrict__ ko, _Float16* __restrict__ vo) {
  __shared__ __align__(16) _Float16 As[128 * 32];  // unpadded: global_load_lds dest
  __shared__ __align__(16) _Float16 Bs[128 * 32];
  const int tid = threadIdx.x;
  const int m0 = blockIdx.x * 128;
  const int n0 = blockIdx.y * 128;
  const int w = tid >> 6, lane = tid & 63;
  const int lr = lane & 15, quad = lane >> 4;
  const int wm = (w & 1) * 64, wn = (w >> 1) * 64;

  f32x4 acc[4][4];
#pragma unroll
  for (int i = 0; i < 4; ++i)
#pragma unroll
    for (int j = 0; j < 4; ++j) acc[i][j] = (f32x4){0.f, 0.f, 0.f, 0.f};

  const int sr1 = tid >> 2, sc = (tid & 3) * 8, sr2 = sr1 + 64;
  const _Float16* Ag1 = A + (size_t)(m0 + sr1) * 1024 + sc;
  const _Float16* Ag2 = A + (size_t)(m0 + sr2) * 1024 + sc;
  const _Float16* Bg1 = W + (size_t)(n0 + sr1) * 1024 + sc;
  const _Float16* Bg2 = W + (size_t)(n0 + sr2) * 1024 + sc;
  // per-lane LDS dest: (tid>>2)*32 + (tid&3)*8 == w*512 + lane*8  (wave base + lane*16B)
  _Float16* Ad1 = &As[sr1 * 32 + sc];
  _Float16* Ad2 = &As[sr2 * 32 + sc];
  _Float16* Bd1 = &Bs[sr1 * 32 + sc];
  _Float16* Bd2 = &Bs[sr2 * 32 + sc];

  for (int kt = 0; kt < 32; ++kt) {
    const int kk = kt * 32;
    __syncthreads();  // WAR: prev tile's frags consumed
    async_ld16(Ag1 + kk, Ad1);
    async_ld16(Ag2 + kk, Ad2);
    async_ld16(Bg1 + kk, Bd1);
    async_ld16(Bg2 + kk, Bd2);
    __syncthreads();  // drains vmcnt: staged tile visible
    fp16x8 af[4], bf[4];
#pragma unroll
    for (int i = 0; i < 4; ++i) {
      af[i] = *(const fp16x8*)&As[(wm + i * 16 + lr) * 32 + quad * 8];
      bf[i] = *(const fp16x8*)&Bs[(wn + i * 16 + lr) * 32 + quad * 8];
    }
#pragma unroll
    for (int i = 0; i < 4; ++i)
#pragma unroll
      for (int j = 0; j < 4; ++j)
        acc[i][j] = __builtin_amdgcn_mfma_f32_16x16x32_f16(af[i], bf[j], acc[i][j], 0, 0, 0);
  }

  const int wsel = n0 >> 10;
  const float* bias = (wsel == 0) ? bq : (wsel == 1) ? bk : bv;
  _Float16* dst = (wsel == 0) ? qo : (wsel == 1) ? ko : vo;
#pragma unroll
  for (int j = 0; j < 4; ++j) {
    const int n = n0 + wn + j * 16 + lr;
    const int nm = n & 1023;
    const float bval = bias[nm];
    const int h = nm >> 6, dd = nm & 63;
#pragma unroll
    for (int i = 0; i < 4; ++i) {
      const int mbase = m0 + wm + i * 16 + quad * 4;
#pragma unroll
      for (int r = 0; r < 4; ++r) {
        const int m = mbase + r;
        const int b = m >> 11, t = m & 2047;
        dst[((size_t)(b * 16 + h) * 2048 + t) * 64 + dd] = (_Float16)(acc[i][j][r] + bval);
      }
    }
  }
}

// ---------------- out projection GEMM (m97 structure) ----------------
__global__ __launch_bounds__(256) void gemm_out(
    const _Float16* __restrict__ A, const _Float16* __restrict__ W,
    const float* __restrict__ bo, float* __restrict__ out) {
  __shared__ __align__(16) _Float16 As[128 * 32];
  __shared__ __align__(16) _Float16 Bs[128 * 32];
  const int tid = threadIdx.x;
  const int m0 = blockIdx.x * 128;
  const int n0 = blockIdx.y * 128;
  const int w = tid >> 6, lane = tid & 63;
  const int lr = lane & 15, quad = lane >> 4;
  const int wm = (w & 1) * 64, wn = (w >> 1) * 64;

  f32x4 acc[4][4];
#pragma unroll
  for (int i = 0; i < 4; ++i)
#pragma unroll
    for (int j = 0; j < 4; ++j) acc[i][j] = (f32x4){0.f, 0.f, 0.f, 0.f};

  const int sr1 = tid >> 2, sc = (tid & 3) * 8, sr2 = sr1 + 64;
  const _Float16* Ag1 = A + (size_t)(m0 + sr1) * 1024 + sc;
  const _Float16* Ag2 = A + (size_t)(m0 + sr2) * 1024 + sc;
  const _Float16* Bg1 = W + (size_t)(n0 + sr1) * 1024 + sc;
  const _Float16* Bg2 = W + (size_t)(n0 + sr2) * 1024 + sc;
  _Float16* Ad1 = &As[sr1 * 32 + sc];
  _Float16* Ad2 = &As[sr2 * 32 + sc];
  _Float16* Bd1 = &Bs[sr1 * 32 + sc];
  _Float16* Bd2 = &Bs[sr2 * 32 + sc];

  for (int kt = 0; kt < 32; ++kt) {
    const int kk = kt * 32;
    __syncthreads();
    async_ld16(Ag1 + kk, Ad1);
    async_ld16(Ag2 + kk, Ad2);
    async_ld16(Bg1 + kk, Bd1);
    async_ld16(Bg2 + kk, Bd2);
    __syncthreads();
    fp16x8 af[4], bf[4];
#pragma unroll
    for (int i = 0; i < 4; ++i) {
      af[i] = *(const fp16x8*)&As[(wm + i * 16 + lr) * 32 + quad * 8];
      bf[i] = *(const fp16x8*)&Bs[(wn + i * 16 + lr) * 32 + quad * 8];
    }
#pragma unroll
    for (int i = 0; i < 4; ++i)
#pragma unroll
      for (int j = 0; j < 4; ++j)
        acc[i][j] = __builtin_amdgcn_mfma_f32_16x16x32_f16(af[i], bf[j], acc[i][j], 0, 0, 0);
  }

#pragma unroll
  for (int j = 0; j < 4; ++j) {
    const int n = n0 + wn + j * 16 + lr;
    const float bval = bo[n];
#pragma unroll
    for (int i = 0; i < 4; ++i) {
      const int mbase = m0 + wm + i * 16 + quad * 4;
#pragma unroll
      for (int r = 0; r < 4; ++r) {
        out[(size_t)(mbase + r) * 1024 + n] = acc[i][j][r] + bval;
      }
    }
  }
}

// ---------------- MFMA causal flash attention, uniform-work pairing ----------------
// Block = (b,h) x q-tile pair (i, 31-i); q-tile = 64 rows; 4 waves x 16 rows.
// Every block runs exactly (i+1)+(32-i) = 33 k-tiles of 64 keys.
__global__ __launch_bounds__(256) void attn(
    const _Float16* __restrict__ q, const _Float16* __restrict__ k,
    const _Float16* __restrict__ v, _Float16* __restrict__ y) {
  __shared__ __align__(16) _Float16 Ks[64 * 72];      // K[kc][d]
  __shared__ __align__(16) _Float16 Vt[64 * 72];      // V^T[d][kc]
  __shared__ __align__(16) _Float16 Ps[4 * 16 * 72];  // per-wave P[16][64]
  const int tid = threadIdx.x;
  const int w = tid >> 6, lane = tid & 63;
  const int lr = lane & 15, quad = lane >> 4;
  const int bh = blockIdx.y;
  const int b = bh >> 4, h = bh & 15;
  const size_t base = (size_t)bh * 2048 * 64;
  _Float16* Pw = &Ps[w * 16 * 72];

  const int kr = tid >> 2, kcb = (tid & 3) * 16;   // K staging: row, col-block
  const int vr = tid & 63, vdb = (tid >> 6) * 16;  // V staging: row (kc), d-block

  const _Float16 qs = (_Float16)(0.125f * LOG2E);  // 1/sqrt(64) * log2(e)

#pragma unroll 1
  for (int part = 0; part < 2; ++part) {
    const int qt = part ? (31 - (int)blockIdx.x) : (int)blockIdx.x;
    const int m0w = qt * 64 + w * 16;  // wave's 16 q-rows

    fp16x8 qf[2];
#pragma unroll
    for (int c = 0; c < 2; ++c) {
      fp16x8 t = *(const fp16x8*)(q + base + (size_t)(m0w + lr) * 64 + c * 32 + quad * 8);
#pragma unroll
      for (int i = 0; i < 8; ++i) t[i] = t[i] * qs;
      qf[c] = t;
    }

    f32x4 oacc[4];
#pragma unroll
    for (int dt = 0; dt < 4; ++dt) oacc[dt] = (f32x4){0.f, 0.f, 0.f, 0.f};
    float m_i[4], l_i[4];
#pragma unroll
    for (int r = 0; r < 4; ++r) { m_i[r] = -3e38f; l_i[r] = 0.f; }

    for (int kt = 0; kt <= qt; ++kt) {
      const _Float16* kg = k + base + (size_t)(kt * 64 + kr) * 64 + kcb;
      const _Float16* vg = v + base + (size_t)(kt * 64 + vr) * 64 + vdb;
      fp16x8 ka = *(const fp16x8*)kg, kb = *(const fp16x8*)(kg + 8);
      fp16x8 va = *(const fp16x8*)vg, vb = *(const fp16x8*)(vg + 8);
      __syncthreads();
      *(fp16x8*)&Ks[kr * 72 + kcb] = ka;
      *(fp16x8*)&Ks[kr * 72 + kcb + 8] = kb;
#pragma unroll
      for (int i = 0; i < 8; ++i) {
        Vt[(vdb + i) * 72 + vr] = va[i];
        Vt[(vdb + 8 + i) * 72 + vr] = vb[i];
      }
      __syncthreads();

      // ---- S = Q K^T (16 x 64) ----
      f32x4 sacc[4];
#pragma unroll
      for (int kct = 0; kct < 4; ++kct) sacc[kct] = (f32x4){0.f, 0.f, 0.f, 0.f};
#pragma unroll
      for (int kct = 0; kct < 4; ++kct) {
        fp16x8 kf0 = *(const fp16x8*)&Ks[(kct * 16 + lr) * 72 + quad * 8];
        fp16x8 kf1 = *(const fp16x8*)&Ks[(kct * 16 + lr) * 72 + 32 + quad * 8];
        sacc[kct] = __builtin_amdgcn_mfma_f32_16x16x32_f16(qf[0], kf0, sacc[kct], 0, 0, 0);
        sacc[kct] = __builtin_amdgcn_mfma_f32_16x16x32_f16(qf[1], kf1, sacc[kct], 0, 0, 0);
      }
      // ---- mask (diagonal tile only) + row max ----
      const bool needmask = (kt == qt);
      const int qrow0 = m0w + quad * 4;
      float rmax[4];
#pragma unroll
      for (int r = 0; r < 4; ++r) {
        if (needmask) {
#pragma unroll
          for (int kct = 0; kct < 4; ++kct) {
            const bool valid = (kt * 64 + kct * 16 + lr) <= (qrow0 + r);
            sacc[kct][r] = valid ? sacc[kct][r] : -3e38f;
          }
        }
        rmax[r] = fmaxf(fmaxf(sacc[0][r], sacc[1][r]), fmaxf(sacc[2][r], sacc[3][r]));
      }
#pragma unroll
      for (int off = 1; off < 16; off <<= 1)
#pragma unroll
        for (int r = 0; r < 4; ++r) rmax[r] = fmaxf(rmax[r], __shfl_xor(rmax[r], off));
      // ---- online update ----
      float corr[4], rsum[4];
#pragma unroll
      for (int r = 0; r < 4; ++r) {
        const float mn = fmaxf(m_i[r], rmax[r]);
        corr[r] = __builtin_amdgcn_exp2f(m_i[r] - mn);
        m_i[r] = mn;
        rsum[r] = 0.f;
      }
      // ---- P = exp2(S - m) -> per-wave LDS (C-layout -> row-major) ----
#pragma unroll
      for (int kct = 0; kct < 4; ++kct)
#pragma unroll
        for (int r = 0; r < 4; ++r) {
          const float p = __builtin_amdgcn_exp2f(sacc[kct][r] - m_i[r]);
          rsum[r] += p;
          Pw[(quad * 4 + r) * 72 + kct * 16 + lr] = (_Float16)p;
        }
#pragma unroll
      for (int off = 1; off < 16; off <<= 1)
#pragma unroll
        for (int r = 0; r < 4; ++r) rsum[r] += __shfl_xor(rsum[r], off);
#pragma unroll
      for (int r = 0; r < 4; ++r) l_i[r] = l_i[r] * corr[r] + rsum[r];
#pragma unroll
      for (int dt = 0; dt < 4; ++dt)
#pragma unroll
        for (int r = 0; r < 4; ++r) oacc[dt][r] *= corr[r];
      // ---- O += P V (P read in A-layout; same-wave LDS ordering) ----
#pragma unroll
      for (int c = 0; c < 2; ++c) {
        fp16x8 pf = *(const fp16x8*)&Pw[lr * 72 + c * 32 + quad * 8];
#pragma unroll
        for (int dt = 0; dt < 4; ++dt) {
          fp16x8 vf = *(const fp16x8*)&Vt[(dt * 16 + lr) * 72 + c * 32 + quad * 8];
          oacc[dt] = __builtin_amdgcn_mfma_f32_16x16x32_f16(pf, vf, oacc[dt], 0, 0, 0);
        }
      }
    }

    // ---- epilogue ----
#pragma unroll
    for (int r = 0; r < 4; ++r) {
      const float inv = 1.f / l_i[r];
      const int tq = m0w + quad * 4 + r;
      _Float16* yp = y + ((size_t)(b * 2048 + tq)) * 1024 + h * 64;
#pragma unroll
      for (int dt = 0; dt < 4; ++dt)
        yp[dt * 16 + lr] = (_Float16)(oacc[dt][r] * inv);
    }
  }
}

extern "C" void kernel_launch(void* const* d_in, const int* in_sizes, int n_in,
                              void* d_out, int out_size, void* d_ws, size_t ws_size,
                              hipStream_t stream) {
  const float* x  = (const float*)d_in[0];
  const float* Wq = (const float*)d_in[1];
  const float* bq = (const float*)d_in[2];
  const float* Wk = (const float*)d_in[3];
  const float* bk = (const float*)d_in[4];
  const float* Wv = (const float*)d_in[5];
  const float* bv = (const float*)d_in[6];
  const float* Wo = (const float*)d_in[7];
  const float* bo = (const float*)d_in[8];

  _Float16* ws   = (_Float16*)d_ws;
  _Float16* xh   = ws;                    // 8388608 (also reused for y)
  _Float16* Wcat = xh + 8388608;          // 3145728
  _Float16* Woh  = Wcat + 3145728;        // 1048576
  _Float16* qh   = Woh + 1048576;         // 8388608  [B*H, T, 64]
  _Float16* kh   = qh + 8388608;
  _Float16* vh   = kh + 8388608;
  _Float16* yh   = xh;                    // alias: x is dead after gemm_qkv

  cast_f32_f16<<<4096, 256, 0, stream>>>(x, xh, 8388608);
  cast_f32_f16<<<512, 256, 0, stream>>>(Wq, Wcat, 1048576);
  cast_f32_f16<<<512, 256, 0, stream>>>(Wk, Wcat + 1048576, 1048576);
  cast_f32_f16<<<512, 256, 0, stream>>>(Wv, Wcat + 2097152, 1048576);
  cast_f32_f16<<<512, 256, 0, stream>>>(Wo, Woh, 1048576);

  gemm_qkv<<<dim3(64, 24), 256, 0, stream>>>(xh, Wcat, bq, bk, bv, qh, kh, vh);
  attn<<<dim3(16, 64), 256, 0, stream>>>(qh, kh, vh, yh);
  gemm_out<<<dim3(64, 8), 256, 0, stream>>>(yh, Woh, bo, (float*)d_out);
}